// Round 11
// baseline (546.549 us; speedup 1.0000x reference)
//
#include <hip/hip_runtime.h>
#include <hip/hip_bf16.h>
#include <cmath>

typedef unsigned short u16;
typedef __attribute__((ext_vector_type(8))) short short8v;
typedef __attribute__((ext_vector_type(8))) unsigned short ushort8v;
typedef __attribute__((ext_vector_type(4))) float f32x4;

#define NPIX 784      // 28*28
#define KP   800
#define NH   800
#define CHUNKB 24576  // 64 rows x 384 B (96 f32)
#define SCROFF 49152  // scratch base in SMEM
#define SCRW   3072   // per-wave scratch: strip [16][96] bf16, PL overlay [64][10] f32

__device__ __forceinline__ u16 f2bf(float f) {
    union { float f; unsigned int u; } v; v.f = f;
    unsigned int u = v.u;
    unsigned int r = (u + 0x7FFFu + ((u >> 16) & 1u)) >> 16;   // RNE
    return (u16)r;
}

__device__ __forceinline__ short8v cvt8(f32x4 v0, f32x4 v1) {
    union { __hip_bfloat162 h; ushort2 u; } a, b, c, d;
    a.h = __float22bfloat162_rn(make_float2(v0[0], v0[1]));
    b.h = __float22bfloat162_rn(make_float2(v0[2], v0[3]));
    c.h = __float22bfloat162_rn(make_float2(v1[0], v1[1]));
    d.h = __float22bfloat162_rn(make_float2(v1[2], v1[3]));
    short8v r;
    r[0] = (short)a.u.x; r[1] = (short)a.u.y; r[2] = (short)b.u.x; r[3] = (short)b.u.y;
    r[4] = (short)c.u.x; r[5] = (short)c.u.y; r[6] = (short)d.u.x; r[7] = (short)d.u.y;
    return r;
}

__device__ __forceinline__ void gload16(const float* g, char* l) {
    __builtin_amdgcn_global_load_lds(
        (const __attribute__((address_space(1))) unsigned int*)g,
        (__attribute__((address_space(3))) unsigned int*)l,
        16, 0, 0);
}

// ---------------------------------------------------------------------------
// Kernel 1: kre = Re(ifft2(ifftshift(tmask))); flag=1 if kre == delta.
// ---------------------------------------------------------------------------
__global__ void k_kre(const float* __restrict__ MRE, const float* __restrict__ MIM,
                      float* __restrict__ KRE, float* __restrict__ FLAG)
{
    __shared__ float msre[784], msim[784], tre[784], tim[784];
    __shared__ float c28[28], s28[28];
    __shared__ int smax;

    const int t = threadIdx.x;   // blockDim = 832
    if (t < 28) {
        float th = (float)t * (6.283185307179586f / 28.0f);
        s28[t] = sinf(th);
        c28[t] = cosf(th);
    }
    if (t == 0) smax = 0;
    if (t < 784) {
        int r = t / 28, c = t - r * 28;
        int idx = ((r + 14) % 28) * 28 + ((c + 14) % 28);   // ifftshift
        msre[t] = MRE[idx];
        msim[t] = MIM[idx];
    }
    __syncthreads();
    if (t < 784) {
        int u = t / 28, cc = t - u * 28;
        float re = 0.f, im = 0.f;
        int ph = 0;
        for (int v = 0; v < 28; ++v) {
            float cr = c28[ph], ci = s28[ph];
            float ar = msre[u * 28 + v], ai = msim[u * 28 + v];
            re += ar * cr - ai * ci;
            im += ar * ci + ai * cr;
            ph += cc; if (ph >= 28) ph -= 28;
        }
        tre[t] = re; tim[t] = im;
    }
    __syncthreads();
    float dev = 0.f;
    if (t < 784) {
        int pr = t / 28, pc = t - pr * 28;
        float s = 0.f;
        int ph = 0;
        for (int u = 0; u < 28; ++u) {
            s += tre[u * 28 + pc] * c28[ph] - tim[u * 28 + pc] * s28[ph];
            ph += pr; if (ph >= 28) ph -= 28;
        }
        s *= (1.0f / 784.0f);
        KRE[t] = s;
        dev = fabsf(s - (t == 0 ? 1.0f : 0.0f));
    }
    #pragma unroll
    for (int m = 32; m >= 1; m >>= 1) dev = fmaxf(dev, __shfl_xor(dev, m, 64));
    if ((t & 63) == 0) atomicMax(&smax, __float_as_int(dev));
    __syncthreads();
    if (t == 0) FLAG[0] = (__int_as_float(smax) < 1e-4f) ? 1.0f : 0.0f;
}

// ---------------------------------------------------------------------------
// Kernel 2: w1_eff packed into MFMA B-fragment order, bf16 (k>=784 -> 0).
// ---------------------------------------------------------------------------
__global__ void k_w1pack(const float* __restrict__ W1, const float* __restrict__ KRE,
                         const float* __restrict__ FLAG, u16* __restrict__ W1P)
{
    const int c = blockIdx.x;    // 0..799
    const int t = threadIdx.x;   // 128
    const bool delta = (FLAG[0] > 0.5f);
    __shared__ float w1d[56 * 56];
    __shared__ float kr[784];

    if (delta) {
        if (t < 100) {
            int k0 = t * 8;
            ushort8v h;
            if (k0 + 7 < NPIX) {
                const float4* wp = (const float4*)(W1 + (size_t)c * NPIX + k0);
                float4 a = wp[0], b = wp[1];
                h[0] = f2bf(a.x); h[1] = f2bf(a.y); h[2] = f2bf(a.z); h[3] = f2bf(a.w);
                h[4] = f2bf(b.x); h[5] = f2bf(b.y); h[6] = f2bf(b.z); h[7] = f2bf(b.w);
            } else {
                #pragma unroll
                for (int e = 0; e < 8; ++e) {
                    int k = k0 + e;
                    h[e] = (k < NPIX) ? f2bf(W1[(size_t)c * NPIX + k]) : (u16)0;
                }
            }
            int kf = k0 >> 5, r = k0 & 31;
            int l  = ((r >> 3) << 4) | (c & 15);
            int nf = c >> 4;
            ((ushort8v*)W1P)[(nf * 25 + kf) * 64 + l] = h;
        }
        return;
    }
    for (int i = t; i < 784; i += 128) kr[i] = KRE[i];
    for (int i = t; i < 3136; i += 128) {
        int r = i / 56, cc = i - r * 56;
        w1d[i] = W1[(size_t)c * NPIX + (r % 28) * 28 + (cc % 28)];
    }
    __syncthreads();
    for (int k = t; k < KP; k += 128) {
        float v = 0.f;
        if (k < NPIX) {
            int krr = k / 28, kcc = k - krr * 28;
            for (int dr = 0; dr < 28; ++dr) {
                const float* wrow = &w1d[(krr + dr) * 56 + kcc];
                const float* krow = &kr[dr * 28];
                #pragma unroll 4
                for (int dc = 0; dc < 28; ++dc) v += wrow[dc] * krow[dc];
            }
        }
        int kf = k >> 5, r = k & 31;
        int l  = ((r >> 3) << 4) | (c & 15);
        int nf = c >> 4;
        W1P[(size_t)(((nf * 25 + kf) * 64 + l) << 3) | (r & 7)] = f2bf(v);
    }
}

// ---------------------------------------------------------------------------
// Kernel 2b: pack W4 per (wave, kt2): W4P2[((w*3+kt2)*64+l)*8+e] =
//   (o<10 && k<800) ? bf16(W4[o][k]) : 0,  k = w*80 + kt2*32 + lk*8 + e, o=lc.
// ---------------------------------------------------------------------------
__global__ void k_w4pack2(const float* __restrict__ W4, u16* __restrict__ W4P2)
{
    int i = blockIdx.x * 256 + threadIdx.x;   // entry = (w*3+kt2)*64 + l, 1920 total
    if (i >= 1920) return;
    int l = i & 63, wk = i >> 6;
    int w = wk / 3, kt2 = wk - w * 3;
    int lc = l & 15, lk = l >> 4;
    ushort8v h;
    #pragma unroll
    for (int e = 0; e < 8; ++e) {
        int k = w * 80 + kt2 * 32 + lk * 8 + e;
        h[e] = (lc < 10 && k < 800) ? f2bf(W4[lc * NH + k]) : (u16)0;
    }
    ((ushort8v*)W4P2)[i] = h;
}

// ---------------------------------------------------------------------------
// Kernel 3: fused GEMM1 + relu + per-wave GEMM2 + log_softmax.
// v11: 2 blocks/CU. LDS = x f32 chunk dbuf (2 x 96 cols, gload_lds, XOR-swz
//      source + read, counted vmcnt, raw barriers) + 10 private wave strips.
//      GEMM2 needs NO cross-wave h: wave w reduces its own 80 cols via a
//      [16][96] bf16 strip transpose (C-layout -> A-frag layout), W4 packed
//      per (w,kt2) by k_w4pack2. Partials in own scratch; 1 syncthreads.
// ---------------------------------------------------------------------------
__global__ __launch_bounds__(640) __attribute__((amdgpu_waves_per_eu(5)))
void k_main(
    const float* __restrict__ X, const u16* __restrict__ W1P,
    const u16* __restrict__ W4P2, const float* __restrict__ B1,
    const float* __restrict__ B4, float* __restrict__ OUT)
{
    __shared__ __align__(16) char SMEM[79872];   // 49152 xdbuf + 30720 scratch
    char* xb = SMEM;

    const int t = threadIdx.x;
    const int row0 = blockIdx.x * 64;
    const int l = t & 63, w = t >> 6;
    const int lc = l & 15, lk = l >> 4;

    // ---- staging slots: chunk = 1536 16B-slots; t<256 owns 3, else 2 ----
    const int q0 = t, q1 = t + 640, q2 = t + 1280;
    const int r_0 = q0 / 24, c_0 = q0 - r_0 * 24;
    const int r_1 = q1 / 24, c_1 = q1 - r_1 * 24;
    const int r_2 = q2 / 24, c_2 = q2 - r_2 * 24;
    // source col16 swizzled: kf*8 + (u ^ (row&7))
    const float* g0 = X + (size_t)(row0 + r_0) * NPIX + (c_0 >> 3) * 32 + (((c_0 & 7) ^ (r_0 & 7)) << 2);
    const float* g1 = X + (size_t)(row0 + r_1) * NPIX + (c_1 >> 3) * 32 + (((c_1 & 7) ^ (r_1 & 7)) << 2);
    const float* g2 = X + (size_t)(row0 + r_2) * NPIX + (c_2 >> 3) * 32 + (((c_2 & 7) ^ (r_2 & 7)) << 2);
    // tail chunk (kt 24): 512 slots, rows x 8; cols >= 784 -> dummy
    const int rt = t >> 3, ut = (t & 7) ^ (rt & 7);
    const float* gt = (ut >= 4) ? X : X + (size_t)(row0 + rt) * NPIX + 768 + (ut << 2);

#define STAGE_CHUNK(cc) do { \
        char* dst_ = xb + ((cc) & 1) * CHUNKB; \
        gload16(g0 + (cc) * 96, dst_ + 16 * q0); \
        gload16(g1 + (cc) * 96, dst_ + 16 * q1); \
        if (t < 256) gload16(g2 + (cc) * 96, dst_ + 16 * q2); \
    } while (0)

    // ---- zero strip pad cols 80..95 (private, persists across m) ----
    u16* strip = (u16*)(SMEM + SCROFF + w * SCRW);
    {
        uint2 z = make_uint2(0u, 0u);
        *(uint2*)((char*)strip + (l >> 2) * 192 + 160 + (l & 3) * 8) = z;
    }

    f32x4 acc[4][5];
    #pragma unroll
    for (int m = 0; m < 4; ++m)
        #pragma unroll
        for (int n = 0; n < 5; ++n) acc[m][n] = (f32x4)(0.0f);

    const short8v* BP = (const short8v*)W1P;
    short8v bb[2][5];
    #pragma unroll
    for (int n = 0; n < 5; ++n)
        bb[0][n] = BP[((w * 5 + n) * 25 + 0) * 64 + l];
    __builtin_amdgcn_sched_barrier(0);

    // ---- prologue: stage chunks 0,1 ----
    STAGE_CHUNK(0);
    STAGE_CHUNK(1);
    if (t < 256) asm volatile("s_waitcnt vmcnt(3)" ::: "memory");
    else         asm volatile("s_waitcnt vmcnt(2)" ::: "memory");
    __builtin_amdgcn_s_barrier();
    __builtin_amdgcn_sched_barrier(0);

    const int swz = (lc & 7) << 4;
    const int aq0 = (lk * 32) ^ swz;     // bit4 of lk*32 is 0 -> aq0^16 = other half

    // ---- GEMM1: 8 chunks x 3 kt (+ tail kt 24), double-buffered ----
    #pragma unroll
    for (int c = 0; c < 8; ++c) {
        const char* bufc = xb + (c & 1) * CHUNKB;
        #pragma unroll
        for (int kf = 0; kf < 3; ++kf) {
            const int kt = c * 3 + kf;
            if (kt < 24) {
                #pragma unroll
                for (int n = 0; n < 5; ++n)
                    bb[(kt + 1) & 1][n] = BP[((w * 5 + n) * 25 + (kt + 1)) * 64 + l];
            }
            const char* ab = bufc + lc * 384 + kf * 128;
            __builtin_amdgcn_s_setprio(1);
            #pragma unroll
            for (int m = 0; m < 4; ++m) {
                f32x4 v0 = *(const f32x4*)(ab + m * 6144 + aq0);
                f32x4 v1 = *(const f32x4*)(ab + m * 6144 + (aq0 ^ 16));
                short8v a = cvt8(v0, v1);
                #pragma unroll
                for (int n = 0; n < 5; ++n)
                    acc[m][n] = __builtin_amdgcn_mfma_f32_16x16x32_bf16(a, bb[kt & 1][n], acc[m][n], 0, 0, 0);
            }
            __builtin_amdgcn_s_setprio(0);
        }
        // boundary: readers of buf(c&1) done; restage it with chunk c+2
        __builtin_amdgcn_sched_barrier(0);
        __builtin_amdgcn_s_barrier();
        if (c < 6) {
            STAGE_CHUNK(c + 2);
            if (t < 256) asm volatile("s_waitcnt vmcnt(3)" ::: "memory");
            else         asm volatile("s_waitcnt vmcnt(2)" ::: "memory");
        } else if (c == 6) {
            if (t < 512) {
                gload16(gt, xb + 16 * t);            // tail -> buf0 (parity of c=8)
                asm volatile("s_waitcnt vmcnt(1)" ::: "memory");
            } else {
                asm volatile("s_waitcnt vmcnt(0)" ::: "memory");
            }
        } else {
            asm volatile("s_waitcnt vmcnt(0)" ::: "memory");
        }
        __builtin_amdgcn_s_barrier();
        __builtin_amdgcn_sched_barrier(0);
    }
    // ---- tail kt 24 (rows x 128 B in buf0) ----
    {
        const char* ab = xb + lc * 128;
        __builtin_amdgcn_s_setprio(1);
        #pragma unroll
        for (int m = 0; m < 4; ++m) {
            f32x4 v0 = *(const f32x4*)(ab + m * 2048 + aq0);
            f32x4 v1 = *(const f32x4*)(ab + m * 2048 + (aq0 ^ 16));
            short8v a = cvt8(v0, v1);
            #pragma unroll
            for (int n = 0; n < 5; ++n)
                acc[m][n] = __builtin_amdgcn_mfma_f32_16x16x32_bf16(a, bb[0][n], acc[m][n], 0, 0, 0);
        }
        __builtin_amdgcn_s_setprio(0);
    }

    // ---- GEMM2 (per-wave, barrier-free): wave w reduces its own 80 cols ----
    float bn[5];
    #pragma unroll
    for (int n = 0; n < 5; ++n) bn[n] = B1[w * 80 + n * 16 + lc];
    const short8v* WP = (const short8v*)W4P2;
    short8v w4f[3];
    #pragma unroll
    for (int kt2 = 0; kt2 < 3; ++kt2)
        w4f[kt2] = WP[(w * 3 + kt2) * 64 + l];

    f32x4 pc[4];
    #pragma unroll
    for (int m = 0; m < 4; ++m) pc[m] = (f32x4)(0.0f);

    #pragma unroll
    for (int m = 0; m < 4; ++m) {
        // strip[r][k] = relu(h) for rows m*16+r, wave-cols k (bf16), k<80
        #pragma unroll
        for (int n = 0; n < 5; ++n)
            #pragma unroll
            for (int j = 0; j < 4; ++j)
                strip[(lk * 4 + j) * 96 + n * 16 + lc] = f2bf(fmaxf(acc[m][n][j] + bn[n], 0.0f));
        // read back as A-fragments, MFMA against W4 frags
        #pragma unroll
        for (int kt2 = 0; kt2 < 3; ++kt2) {
            short8v a2 = *(const short8v*)(strip + lc * 96 + kt2 * 32 + lk * 8);
            pc[m] = __builtin_amdgcn_mfma_f32_16x16x32_bf16(a2, w4f[kt2], pc[m], 0, 0, 0);
        }
    }

    // ---- partials into own scratch (overlay; strip dead) ----
    {
        float* PLf = (float*)strip;
        if (lc < 10) {
            #pragma unroll
            for (int m = 0; m < 4; ++m)
                #pragma unroll
                for (int j = 0; j < 4; ++j)
                    PLf[(m * 16 + lk * 4 + j) * 10 + lc] = pc[m][j];
        }
    }
    __syncthreads();

    // ---- combine + bias + log_softmax, one row per thread ----
    if (t < 64) {
        float lg[10];
        #pragma unroll
        for (int o = 0; o < 10; ++o) lg[o] = B4[o];
        #pragma unroll
        for (int w2 = 0; w2 < 10; ++w2) {
            const float* PLw = (const float*)(SMEM + SCROFF + w2 * SCRW);
            #pragma unroll
            for (int o = 0; o < 10; ++o) lg[o] += PLw[t * 10 + o];
        }
        float mx = lg[0];
        #pragma unroll
        for (int o = 1; o < 10; ++o) mx = fmaxf(mx, lg[o]);
        float se = 0.f;
        #pragma unroll
        for (int o = 0; o < 10; ++o) se += expf(lg[o] - mx);
        float lse = logf(se);
        float* op = OUT + (size_t)(row0 + t) * 10;
        #pragma unroll
        for (int o = 0; o < 10; ++o) op[o] = lg[o] - mx - lse;
    }
#undef STAGE_CHUNK
}

// ---------------------------------------------------------------------------
extern "C" void kernel_launch(void* const* d_in, const int* in_sizes, int n_in,
                              void* d_out, int out_size, void* d_ws, size_t ws_size,
                              hipStream_t stream)
{
    const float* X   = (const float*)d_in[0];
    const float* MRE = (const float*)d_in[1];
    const float* MIM = (const float*)d_in[2];
    const float* W1  = (const float*)d_in[3];
    const float* B1  = (const float*)d_in[4];
    const float* W4  = (const float*)d_in[5];
    const float* B4  = (const float*)d_in[6];
    float* OUT = (float*)d_out;

    float* kre  = (float*)d_ws;                          // 784 f32
    float* flag = kre + 784;                             // 1 f32
    u16*   w1p  = (u16*)((char*)d_ws + 4096);            // 1.28 MB
    u16*   w4p2 = (u16*)((char*)d_ws + 4096 + 1310720);  // 30720 B

    k_kre<<<1, 832, 0, stream>>>(MRE, MIM, kre, flag);
    k_w1pack<<<800, 128, 0, stream>>>(W1, kre, flag, w1p);
    k_w4pack2<<<8, 256, 0, stream>>>(W4, w4p2);
    k_main<<<512, 640, 0, stream>>>(X, w1p, w4p2, B1, B4, OUT);
}

// Round 12
// 448.818 us; speedup vs baseline: 1.2178x; 1.2178x over previous
//
#include <hip/hip_runtime.h>
#include <hip/hip_bf16.h>
#include <cmath>

typedef unsigned short u16;
typedef __attribute__((ext_vector_type(8))) short short8v;
typedef __attribute__((ext_vector_type(8))) unsigned short ushort8v;
typedef __attribute__((ext_vector_type(4))) float f32x4;

#define NPIX 784      // 28*28
#define KP   800
#define NH   800
#define BM   128      // rows per block; grid = 256 = 1 block/CU
#define CHUNKB 49152  // 128 rows x 384 B (96 f32)
#define PLOFF  98304  // PL region base (after x dbuf)
#define PLW    5120   // per-wave PL: [128][10] f32

__device__ __forceinline__ u16 f2bf(float f) {
    union { float f; unsigned int u; } v; v.f = f;
    unsigned int u = v.u;
    unsigned int r = (u + 0x7FFFu + ((u >> 16) & 1u)) >> 16;   // RNE
    return (u16)r;
}

__device__ __forceinline__ short8v cvt8(f32x4 v0, f32x4 v1) {
    union { __hip_bfloat162 h; ushort2 u; } a, b, c, d;
    a.h = __float22bfloat162_rn(make_float2(v0[0], v0[1]));
    b.h = __float22bfloat162_rn(make_float2(v0[2], v0[3]));
    c.h = __float22bfloat162_rn(make_float2(v1[0], v1[1]));
    d.h = __float22bfloat162_rn(make_float2(v1[2], v1[3]));
    short8v r;
    r[0] = (short)a.u.x; r[1] = (short)a.u.y; r[2] = (short)b.u.x; r[3] = (short)b.u.y;
    r[4] = (short)c.u.x; r[5] = (short)c.u.y; r[6] = (short)d.u.x; r[7] = (short)d.u.y;
    return r;
}

__device__ __forceinline__ void gload16(const float* g, char* l) {
    __builtin_amdgcn_global_load_lds(
        (const __attribute__((address_space(1))) unsigned int*)g,
        (__attribute__((address_space(3))) unsigned int*)l,
        16, 0, 0);
}

// ---------------------------------------------------------------------------
// Kernel 1: kre = Re(ifft2(ifftshift(tmask))); flag=1 if kre == delta.
// ---------------------------------------------------------------------------
__global__ void k_kre(const float* __restrict__ MRE, const float* __restrict__ MIM,
                      float* __restrict__ KRE, float* __restrict__ FLAG)
{
    __shared__ float msre[784], msim[784], tre[784], tim[784];
    __shared__ float c28[28], s28[28];
    __shared__ int smax;

    const int t = threadIdx.x;   // blockDim = 832
    if (t < 28) {
        float th = (float)t * (6.283185307179586f / 28.0f);
        s28[t] = sinf(th);
        c28[t] = cosf(th);
    }
    if (t == 0) smax = 0;
    if (t < 784) {
        int r = t / 28, c = t - r * 28;
        int idx = ((r + 14) % 28) * 28 + ((c + 14) % 28);   // ifftshift
        msre[t] = MRE[idx];
        msim[t] = MIM[idx];
    }
    __syncthreads();
    if (t < 784) {
        int u = t / 28, cc = t - u * 28;
        float re = 0.f, im = 0.f;
        int ph = 0;
        for (int v = 0; v < 28; ++v) {
            float cr = c28[ph], ci = s28[ph];
            float ar = msre[u * 28 + v], ai = msim[u * 28 + v];
            re += ar * cr - ai * ci;
            im += ar * ci + ai * cr;
            ph += cc; if (ph >= 28) ph -= 28;
        }
        tre[t] = re; tim[t] = im;
    }
    __syncthreads();
    float dev = 0.f;
    if (t < 784) {
        int pr = t / 28, pc = t - pr * 28;
        float s = 0.f;
        int ph = 0;
        for (int u = 0; u < 28; ++u) {
            s += tre[u * 28 + pc] * c28[ph] - tim[u * 28 + pc] * s28[ph];
            ph += pr; if (ph >= 28) ph -= 28;
        }
        s *= (1.0f / 784.0f);
        KRE[t] = s;
        dev = fabsf(s - (t == 0 ? 1.0f : 0.0f));
    }
    #pragma unroll
    for (int m = 32; m >= 1; m >>= 1) dev = fmaxf(dev, __shfl_xor(dev, m, 64));
    if ((t & 63) == 0) atomicMax(&smax, __float_as_int(dev));
    __syncthreads();
    if (t == 0) FLAG[0] = (__int_as_float(smax) < 1e-4f) ? 1.0f : 0.0f;
}

// ---------------------------------------------------------------------------
// Kernel 2: w1_eff packed into MFMA B-fragment order, bf16 (k>=784 -> 0).
// ---------------------------------------------------------------------------
__global__ void k_w1pack(const float* __restrict__ W1, const float* __restrict__ KRE,
                         const float* __restrict__ FLAG, u16* __restrict__ W1P)
{
    const int c = blockIdx.x;    // 0..799
    const int t = threadIdx.x;   // 128
    const bool delta = (FLAG[0] > 0.5f);
    __shared__ float w1d[56 * 56];
    __shared__ float kr[784];

    if (delta) {
        if (t < 100) {
            int k0 = t * 8;
            ushort8v h;
            if (k0 + 7 < NPIX) {
                const float4* wp = (const float4*)(W1 + (size_t)c * NPIX + k0);
                float4 a = wp[0], b = wp[1];
                h[0] = f2bf(a.x); h[1] = f2bf(a.y); h[2] = f2bf(a.z); h[3] = f2bf(a.w);
                h[4] = f2bf(b.x); h[5] = f2bf(b.y); h[6] = f2bf(b.z); h[7] = f2bf(b.w);
            } else {
                #pragma unroll
                for (int e = 0; e < 8; ++e) {
                    int k = k0 + e;
                    h[e] = (k < NPIX) ? f2bf(W1[(size_t)c * NPIX + k]) : (u16)0;
                }
            }
            int kf = k0 >> 5, r = k0 & 31;
            int l  = ((r >> 3) << 4) | (c & 15);
            int nf = c >> 4;
            ((ushort8v*)W1P)[(nf * 25 + kf) * 64 + l] = h;
        }
        return;
    }
    for (int i = t; i < 784; i += 128) kr[i] = KRE[i];
    for (int i = t; i < 3136; i += 128) {
        int r = i / 56, cc = i - r * 56;
        w1d[i] = W1[(size_t)c * NPIX + (r % 28) * 28 + (cc % 28)];
    }
    __syncthreads();
    for (int k = t; k < KP; k += 128) {
        float v = 0.f;
        if (k < NPIX) {
            int krr = k / 28, kcc = k - krr * 28;
            for (int dr = 0; dr < 28; ++dr) {
                const float* wrow = &w1d[(krr + dr) * 56 + kcc];
                const float* krow = &kr[dr * 28];
                #pragma unroll 4
                for (int dc = 0; dc < 28; ++dc) v += wrow[dc] * krow[dc];
            }
        }
        int kf = k >> 5, r = k & 31;
        int l  = ((r >> 3) << 4) | (c & 15);
        int nf = c >> 4;
        W1P[(size_t)(((nf * 25 + kf) * 64 + l) << 3) | (r & 7)] = f2bf(v);
    }
}

// ---------------------------------------------------------------------------
// Kernel 2b: pack W4 per (wave, kt2): W4P2[((w*3+kt2)*64+l)*8+e] =
//   (o<10 && k<800) ? bf16(W4[o][k]) : 0,  k = w*80 + kt2*32 + lk*8 + e, o=lc.
// ---------------------------------------------------------------------------
__global__ void k_w4pack2(const float* __restrict__ W4, u16* __restrict__ W4P2)
{
    int i = blockIdx.x * 256 + threadIdx.x;   // entry = (w*3+kt2)*64 + l, 1920 total
    if (i >= 1920) return;
    int l = i & 63, wk = i >> 6;
    int w = wk / 3, kt2 = wk - w * 3;
    int lc = l & 15, lk = l >> 4;
    ushort8v h;
    #pragma unroll
    for (int e = 0; e < 8; ++e) {
        int k = w * 80 + kt2 * 32 + lk * 8 + e;
        h[e] = (lc < 10 && k < 800) ? f2bf(W4[lc * NH + k]) : (u16)0;
    }
    ((ushort8v*)W4P2)[i] = h;
}

// ---------------------------------------------------------------------------
// Kernel 3: fused GEMM1 + relu + per-wave GEMM2 + log_softmax.
// v12: BM=128, grid=256 (exactly 1 block/CU; LDS 149.5 KB enforces it).
//      Per wave 8 M x 5 N frags -> acc 160 AGPR (cap 256), 40 MFMA per kt
//      cover B depth-1 latency; B L2 traffic halves. X staged f32 via
//      v11-verified swizzled gload_lds chunk dbuf (96-col chunks, counted
//      vmcnt, raw barriers). GEMM2 = v11-verified per-wave strip transpose
//      (strips overlay dead x-buffer; PL in own region). waves_per_eu(3,3)
//      pinned (single-arg variant caused r11's total-spill disaster).
// ---------------------------------------------------------------------------
__global__ __launch_bounds__(640) __attribute__((amdgpu_waves_per_eu(3, 3)))
void k_main(
    const float* __restrict__ X, const u16* __restrict__ W1P,
    const u16* __restrict__ W4P2, const float* __restrict__ B1,
    const float* __restrict__ B4, float* __restrict__ OUT)
{
    __shared__ __align__(16) char SMEM[149504];  // 2x49152 xdbuf + 51200 PL
    char* xb = SMEM;

    const int t = threadIdx.x;
    const int row0 = blockIdx.x * BM;
    const int l = t & 63, w = t >> 6;
    const int lc = l & 15, lk = l >> 4;

    // ---- staging slots: chunk = 3072 16B-slots; t<512 owns 5, else 4 ----
    int  sr[5], scb[5];
    const float* gp[5];
    #pragma unroll
    for (int i = 0; i < 5; ++i) {
        int slot = t + 640 * i;
        int r = slot / 24, cgr = slot - r * 24;              // 24 granules/row
        sr[i] = slot;
        scb[i] = 0;
        gp[i] = X + (size_t)(row0 + r) * NPIX + ((cgr >> 3) << 5) + (((cgr & 7) ^ (r & 7)) << 2);
    }
    // tail chunk (kt 24): 1024 slots (128 rows x 8 granules); t<384 owns 2
    const float* gt[2];
    int st[2];
    #pragma unroll
    for (int i = 0; i < 2; ++i) {
        int slot = t + 640 * i;
        int rt = slot >> 3, ut = (slot & 7) ^ (rt & 7);
        st[i] = slot;
        gt[i] = (ut >= 4) ? X : X + (size_t)(row0 + rt) * NPIX + 768 + (ut << 2);
    }

#define STAGE_CHUNK(cc) do { \
        char* dst_ = xb + ((cc) & 1) * CHUNKB; \
        gload16(gp[0] + (cc) * 96, dst_ + 16 * sr[0]); \
        gload16(gp[1] + (cc) * 96, dst_ + 16 * sr[1]); \
        gload16(gp[2] + (cc) * 96, dst_ + 16 * sr[2]); \
        gload16(gp[3] + (cc) * 96, dst_ + 16 * sr[3]); \
        if (t < 512) gload16(gp[4] + (cc) * 96, dst_ + 16 * sr[4]); \
    } while (0)

    f32x4 acc[8][5];
    #pragma unroll
    for (int m = 0; m < 8; ++m)
        #pragma unroll
        for (int n = 0; n < 5; ++n) acc[m][n] = (f32x4)(0.0f);

    const short8v* BP = (const short8v*)W1P;
    short8v bb[2][5];
    #pragma unroll
    for (int n = 0; n < 5; ++n)
        bb[0][n] = BP[((w * 5 + n) * 25 + 0) * 64 + l];
    __builtin_amdgcn_sched_barrier(0);

    // ---- prologue: stage chunks 0,1 ----
    STAGE_CHUNK(0);
    STAGE_CHUNK(1);
    if (t < 512) asm volatile("s_waitcnt vmcnt(5)" ::: "memory");
    else         asm volatile("s_waitcnt vmcnt(4)" ::: "memory");
    __builtin_amdgcn_s_barrier();
    __builtin_amdgcn_sched_barrier(0);

    const int aq0 = (lk * 32) ^ ((lc & 7) << 4);

    // ---- GEMM1: 8 chunks x 3 kt, double-buffered, counted vmcnt ----
    #pragma unroll
    for (int c = 0; c < 8; ++c) {
        const char* bufc = xb + (c & 1) * CHUNKB;
        #pragma unroll
        for (int kf = 0; kf < 3; ++kf) {
            const int kt = c * 3 + kf;
            if (kt < 24) {
                #pragma unroll
                for (int n = 0; n < 5; ++n)
                    bb[(kt + 1) & 1][n] = BP[((w * 5 + n) * 25 + (kt + 1)) * 64 + l];
            }
            const char* ab = bufc + lc * 384 + kf * 128;
            __builtin_amdgcn_s_setprio(1);
            #pragma unroll
            for (int m = 0; m < 8; ++m) {
                f32x4 v0 = *(const f32x4*)(ab + m * 6144 + aq0);
                f32x4 v1 = *(const f32x4*)(ab + m * 6144 + (aq0 ^ 16));
                short8v a = cvt8(v0, v1);
                #pragma unroll
                for (int n = 0; n < 5; ++n)
                    acc[m][n] = __builtin_amdgcn_mfma_f32_16x16x32_bf16(a, bb[kt & 1][n], acc[m][n], 0, 0, 0);
            }
            __builtin_amdgcn_s_setprio(0);
        }
        __builtin_amdgcn_sched_barrier(0);
        __builtin_amdgcn_s_barrier();          // readers of buf(c&1) done
        if (c < 6) {
            STAGE_CHUNK(c + 2);
            if (t < 512) asm volatile("s_waitcnt vmcnt(5)" ::: "memory");
            else         asm volatile("s_waitcnt vmcnt(4)" ::: "memory");
        } else if (c == 6) {
            gload16(gt[0], xb + 16 * st[0]);   // tail -> buf0
            if (t < 384) {
                gload16(gt[1], xb + 16 * st[1]);
                asm volatile("s_waitcnt vmcnt(2)" ::: "memory");
            } else {
                asm volatile("s_waitcnt vmcnt(1)" ::: "memory");
            }
        } else {
            asm volatile("s_waitcnt vmcnt(0)" ::: "memory");
        }
        __builtin_amdgcn_s_barrier();          // next buffer ready
        __builtin_amdgcn_sched_barrier(0);
    }
    // ---- tail kt 24 (128 rows x 128 B in buf0) ----
    {
        const char* ab = xb + lc * 128;
        __builtin_amdgcn_s_setprio(1);
        #pragma unroll
        for (int m = 0; m < 8; ++m) {
            f32x4 v0 = *(const f32x4*)(ab + m * 2048 + aq0);
            f32x4 v1 = *(const f32x4*)(ab + m * 2048 + (aq0 ^ 16));
            short8v a = cvt8(v0, v1);
            #pragma unroll
            for (int n = 0; n < 5; ++n)
                acc[m][n] = __builtin_amdgcn_mfma_f32_16x16x32_bf16(a, bb[0][n], acc[m][n], 0, 0, 0);
        }
        __builtin_amdgcn_s_setprio(0);
    }
    __syncthreads();   // x-buffer dead; strips may overlay it

    // ---- GEMM2 (per-wave): wave w reduces its own 80 h-cols ----
    u16* strip = (u16*)(xb + w * 3072);        // [16][96] bf16, private
    {   // zero pad cols 80..95 once
        uint2 z = make_uint2(0u, 0u);
        *(uint2*)((char*)strip + (l >> 2) * 192 + 160 + (l & 3) * 8) = z;
    }
    float bn[5];
    #pragma unroll
    for (int n = 0; n < 5; ++n) bn[n] = B1[w * 80 + n * 16 + lc];
    const short8v* WP = (const short8v*)W4P2;
    short8v w4f[3];
    #pragma unroll
    for (int kt2 = 0; kt2 < 3; ++kt2)
        w4f[kt2] = WP[(w * 3 + kt2) * 64 + l];

    float* PLf = (float*)(SMEM + PLOFF + w * PLW);
    #pragma unroll
    for (int m = 0; m < 8; ++m) {
        #pragma unroll
        for (int n = 0; n < 5; ++n)
            #pragma unroll
            for (int j = 0; j < 4; ++j)
                strip[(lk * 4 + j) * 96 + n * 16 + lc] = f2bf(fmaxf(acc[m][n][j] + bn[n], 0.0f));
        f32x4 pc = (f32x4)(0.0f);
        #pragma unroll
        for (int kt2 = 0; kt2 < 3; ++kt2) {
            short8v a2 = *(const short8v*)(strip + lc * 96 + kt2 * 32 + lk * 8);
            pc = __builtin_amdgcn_mfma_f32_16x16x32_bf16(a2, w4f[kt2], pc, 0, 0, 0);
        }
        if (lc < 10) {
            #pragma unroll
            for (int j = 0; j < 4; ++j)
                PLf[(m * 16 + lk * 4 + j) * 10 + lc] = pc[j];
        }
    }
    __syncthreads();

    // ---- combine + bias + log_softmax, one row per thread ----
    if (t < BM) {
        float lg[10];
        #pragma unroll
        for (int o = 0; o < 10; ++o) lg[o] = B4[o];
        #pragma unroll
        for (int w2 = 0; w2 < 10; ++w2) {
            const float* PLw = (const float*)(SMEM + PLOFF + w2 * PLW);
            #pragma unroll
            for (int o = 0; o < 10; ++o) lg[o] += PLw[t * 10 + o];
        }
        float mx = lg[0];
        #pragma unroll
        for (int o = 1; o < 10; ++o) mx = fmaxf(mx, lg[o]);
        float se = 0.f;
        #pragma unroll
        for (int o = 0; o < 10; ++o) se += expf(lg[o] - mx);
        float lse = logf(se);
        float* op = OUT + (size_t)(row0 + t) * 10;
        #pragma unroll
        for (int o = 0; o < 10; ++o) op[o] = lg[o] - mx - lse;
    }
#undef STAGE_CHUNK
}

// ---------------------------------------------------------------------------
extern "C" void kernel_launch(void* const* d_in, const int* in_sizes, int n_in,
                              void* d_out, int out_size, void* d_ws, size_t ws_size,
                              hipStream_t stream)
{
    const float* X   = (const float*)d_in[0];
    const float* MRE = (const float*)d_in[1];
    const float* MIM = (const float*)d_in[2];
    const float* W1  = (const float*)d_in[3];
    const float* B1  = (const float*)d_in[4];
    const float* W4  = (const float*)d_in[5];
    const float* B4  = (const float*)d_in[6];
    float* OUT = (float*)d_out;

    float* kre  = (float*)d_ws;                          // 784 f32
    float* flag = kre + 784;                             // 1 f32
    u16*   w1p  = (u16*)((char*)d_ws + 4096);            // 1.28 MB
    u16*   w4p2 = (u16*)((char*)d_ws + 4096 + 1310720);  // 30720 B

    k_kre<<<1, 832, 0, stream>>>(MRE, MIM, kre, flag);
    k_w1pack<<<800, 128, 0, stream>>>(W1, kre, flag, w1p);
    k_w4pack2<<<8, 256, 0, stream>>>(W4, w4p2);
    k_main<<<256, 640, 0, stream>>>(X, w1p, w4p2, B1, B4, OUT);
}

// Round 13
// 68.831 us; speedup vs baseline: 7.9404x; 6.5206x over previous
//
#include <hip/hip_runtime.h>
#include <hip/hip_bf16.h>
#include <cmath>

typedef unsigned short u16;
typedef __attribute__((ext_vector_type(8))) short short8v;
typedef __attribute__((ext_vector_type(8))) unsigned short ushort8v;
typedef __attribute__((ext_vector_type(4))) float f32x4;

#define NPIX 784      // 28*28
#define KP   800
#define NH   800
#define LSTR 424      // LDS half-tile row stride, bf16 (848 B rows; 848%128=80 -> spread)

__device__ __forceinline__ u16 f2bf(float f) {
    union { float f; unsigned int u; } v; v.f = f;
    unsigned int u = v.u;
    unsigned int r = (u + 0x7FFFu + ((u >> 16) & 1u)) >> 16;   // RNE
    return (u16)r;
}

__device__ __forceinline__ short8v cvt8(f32x4 v0, f32x4 v1) {
    union { __hip_bfloat162 h; ushort2 u; } a, b, c, d;
    a.h = __float22bfloat162_rn(make_float2(v0[0], v0[1]));
    b.h = __float22bfloat162_rn(make_float2(v0[2], v0[3]));
    c.h = __float22bfloat162_rn(make_float2(v1[0], v1[1]));
    d.h = __float22bfloat162_rn(make_float2(v1[2], v1[3]));
    short8v r;
    r[0] = (short)a.u.x; r[1] = (short)a.u.y; r[2] = (short)b.u.x; r[3] = (short)b.u.y;
    r[4] = (short)c.u.x; r[5] = (short)c.u.y; r[6] = (short)d.u.x; r[7] = (short)d.u.y;
    return r;
}

// ---------------------------------------------------------------------------
// Kernel 1: kre = Re(ifft2(ifftshift(tmask))); flag=1 if kre == delta.
// ---------------------------------------------------------------------------
__global__ void k_kre(const float* __restrict__ MRE, const float* __restrict__ MIM,
                      float* __restrict__ KRE, float* __restrict__ FLAG)
{
    __shared__ float msre[784], msim[784], tre[784], tim[784];
    __shared__ float c28[28], s28[28];
    __shared__ int smax;

    const int t = threadIdx.x;   // blockDim = 832
    if (t < 28) {
        float th = (float)t * (6.283185307179586f / 28.0f);
        s28[t] = sinf(th);
        c28[t] = cosf(th);
    }
    if (t == 0) smax = 0;
    if (t < 784) {
        int r = t / 28, c = t - r * 28;
        int idx = ((r + 14) % 28) * 28 + ((c + 14) % 28);   // ifftshift
        msre[t] = MRE[idx];
        msim[t] = MIM[idx];
    }
    __syncthreads();
    if (t < 784) {
        int u = t / 28, cc = t - u * 28;
        float re = 0.f, im = 0.f;
        int ph = 0;
        for (int v = 0; v < 28; ++v) {
            float cr = c28[ph], ci = s28[ph];
            float ar = msre[u * 28 + v], ai = msim[u * 28 + v];
            re += ar * cr - ai * ci;
            im += ar * ci + ai * cr;
            ph += cc; if (ph >= 28) ph -= 28;
        }
        tre[t] = re; tim[t] = im;
    }
    __syncthreads();
    float dev = 0.f;
    if (t < 784) {
        int pr = t / 28, pc = t - pr * 28;
        float s = 0.f;
        int ph = 0;
        for (int u = 0; u < 28; ++u) {
            s += tre[u * 28 + pc] * c28[ph] - tim[u * 28 + pc] * s28[ph];
            ph += pr; if (ph >= 28) ph -= 28;
        }
        s *= (1.0f / 784.0f);
        KRE[t] = s;
        dev = fabsf(s - (t == 0 ? 1.0f : 0.0f));
    }
    #pragma unroll
    for (int m = 32; m >= 1; m >>= 1) dev = fmaxf(dev, __shfl_xor(dev, m, 64));
    if ((t & 63) == 0) atomicMax(&smax, __float_as_int(dev));
    __syncthreads();
    if (t == 0) FLAG[0] = (__int_as_float(smax) < 1e-4f) ? 1.0f : 0.0f;
}

// ---------------------------------------------------------------------------
// Kernel 2: w1_eff packed into MFMA B-fragment order, bf16 (k>=784 -> 0).
// ---------------------------------------------------------------------------
__global__ void k_w1pack(const float* __restrict__ W1, const float* __restrict__ KRE,
                         const float* __restrict__ FLAG, u16* __restrict__ W1P)
{
    const int c = blockIdx.x;    // 0..799
    const int t = threadIdx.x;   // 128
    const bool delta = (FLAG[0] > 0.5f);
    __shared__ float w1d[56 * 56];
    __shared__ float kr[784];

    if (delta) {
        if (t < 100) {
            int k0 = t * 8;
            ushort8v h;
            if (k0 + 7 < NPIX) {
                const float4* wp = (const float4*)(W1 + (size_t)c * NPIX + k0);
                float4 a = wp[0], b = wp[1];
                h[0] = f2bf(a.x); h[1] = f2bf(a.y); h[2] = f2bf(a.z); h[3] = f2bf(a.w);
                h[4] = f2bf(b.x); h[5] = f2bf(b.y); h[6] = f2bf(b.z); h[7] = f2bf(b.w);
            } else {
                #pragma unroll
                for (int e = 0; e < 8; ++e) {
                    int k = k0 + e;
                    h[e] = (k < NPIX) ? f2bf(W1[(size_t)c * NPIX + k]) : (u16)0;
                }
            }
            int kf = k0 >> 5, r = k0 & 31;
            int l  = ((r >> 3) << 4) | (c & 15);
            int nf = c >> 4;
            ((ushort8v*)W1P)[(nf * 25 + kf) * 64 + l] = h;
        }
        return;
    }
    for (int i = t; i < 784; i += 128) kr[i] = KRE[i];
    for (int i = t; i < 3136; i += 128) {
        int r = i / 56, cc = i - r * 56;
        w1d[i] = W1[(size_t)c * NPIX + (r % 28) * 28 + (cc % 28)];
    }
    __syncthreads();
    for (int k = t; k < KP; k += 128) {
        float v = 0.f;
        if (k < NPIX) {
            int krr = k / 28, kcc = k - krr * 28;
            for (int dr = 0; dr < 28; ++dr) {
                const float* wrow = &w1d[(krr + dr) * 56 + kcc];
                const float* krow = &kr[dr * 28];
                #pragma unroll 4
                for (int dc = 0; dc < 28; ++dc) v += wrow[dc] * krow[dc];
            }
        }
        int kf = k >> 5, r = k & 31;
        int l  = ((r >> 3) << 4) | (c & 15);
        int nf = c >> 4;
        W1P[(size_t)(((nf * 25 + kf) * 64 + l) << 3) | (r & 7)] = f2bf(v);
    }
}

// ---------------------------------------------------------------------------
// Kernel 2b: pack W4 per (wave, kt2): W4P2[((w*3+kt2)*64+l)*8+e] =
//   (o<10 && k<800) ? bf16(W4[o][k]) : 0,  k = w*80 + kt2*32 + lk*8 + e, o=lc.
// ---------------------------------------------------------------------------
__global__ void k_w4pack2(const float* __restrict__ W4, u16* __restrict__ W4P2)
{
    int i = blockIdx.x * 256 + threadIdx.x;   // entry = (w*3+kt2)*64 + l, 1920 total
    if (i >= 1920) return;
    int l = i & 63, wk = i >> 6;
    int w = wk / 3, kt2 = wk - w * 3;
    int lc = l & 15, lk = l >> 4;
    ushort8v h;
    #pragma unroll
    for (int e = 0; e < 8; ++e) {
        int k = w * 80 + kt2 * 32 + lk * 8 + e;
        h[e] = (lc < 10 && k < 800) ? f2bf(W4[lc * NH + k]) : (u16)0;
    }
    ((ushort8v*)W4P2)[i] = h;
}

// ---------------------------------------------------------------------------
// Kernel 3: fused GEMM1 + relu + per-wave GEMM2 + log_softmax.
// v13: BM=64, HALF-K LDS tile (64x424 bf16 = 54.3 KB) -> 2 blocks/CU
//      (20 waves, 5/SIMD): block B computes while block A (re)stages; per-kt
//      B-latency covered by 2x the waves. Register envelope = v5's proven
//      non-spill set (acc 80 AGPR + bb 40 + <=10 transients). Half-0 (kt
//      0..11) staged, computed; raw barrier; half-1 (kt 12..24, zero-pad
//      784..799) restaged into the same buffer; computed. GEMM2 = r12's
//      verified per-wave strip transpose; strips+PL overlay the dead x-buf.
// ---------------------------------------------------------------------------
__global__ __launch_bounds__(640) __attribute__((amdgpu_waves_per_eu(3, 3)))
void k_main(
    const float* __restrict__ X, const u16* __restrict__ W1P,
    const u16* __restrict__ W4P2, const float* __restrict__ B1,
    const float* __restrict__ B4, float* __restrict__ OUT)
{
    __shared__ __align__(16) u16 As[64 * LSTR];   // 54272 B
    const int t = threadIdx.x;
    const int row0 = blockIdx.x * 64;
    const int l = t & 63, w = t >> 6;
    const int lc = l & 15, lk = l >> 4;

    f32x4 acc[4][5];
    #pragma unroll
    for (int m = 0; m < 4; ++m)
        #pragma unroll
        for (int n = 0; n < 5; ++n) acc[m][n] = (f32x4)(0.0f);

    const short8v* BP = (const short8v*)W1P;
    short8v bb[2][5];
    #pragma unroll
    for (int n = 0; n < 5; ++n)
        bb[0][n] = BP[((w * 5 + n) * 25 + 0) * 64 + l];

    // ---- stage half-0: cols [0,384) = 3072 units of 8 f32 ----
    #pragma unroll
    for (int i = 0; i < 5; ++i) {
        int u = t + 640 * i;
        if (i < 4 || u < 3072) {
            int row = u / 48, uc = u - row * 48;
            const float* g = X + (size_t)(row0 + row) * NPIX + uc * 8;
            f32x4 v0 = *(const f32x4*)(g);
            f32x4 v1 = *(const f32x4*)(g + 4);
            *(short8v*)(As + row * LSTR + uc * 8) = cvt8(v0, v1);
        }
    }
    asm volatile("s_waitcnt lgkmcnt(0)" ::: "memory");
    __builtin_amdgcn_s_barrier();
    __builtin_amdgcn_sched_barrier(0);

    // ---- kt 0..11 (half-0), depth-1 B prefetch ----
    #pragma unroll
    for (int kt = 0; kt < 12; ++kt) {
        #pragma unroll
        for (int n = 0; n < 5; ++n)
            bb[(kt + 1) & 1][n] = BP[((w * 5 + n) * 25 + (kt + 1)) * 64 + l];
        const u16* ab = As + lc * LSTR + kt * 32 + lk * 8;
        __builtin_amdgcn_s_setprio(1);
        #pragma unroll
        for (int m = 0; m < 4; ++m) {
            short8v a = *(const short8v*)(ab + m * (16 * LSTR));
            #pragma unroll
            for (int n = 0; n < 5; ++n)
                acc[m][n] = __builtin_amdgcn_mfma_f32_16x16x32_bf16(a, bb[kt & 1][n], acc[m][n], 0, 0, 0);
        }
        __builtin_amdgcn_s_setprio(0);
    }
    asm volatile("s_waitcnt lgkmcnt(0)" ::: "memory");
    __builtin_amdgcn_s_barrier();              // half-0 reads done everywhere
    __builtin_amdgcn_sched_barrier(0);

    // ---- stage half-1: cols [384,800) = 3328 units (52/row); >=784 -> 0 ----
    #pragma unroll
    for (int i = 0; i < 6; ++i) {
        int u = t + 640 * i;
        if (i < 5 || u < 3328) {
            int row = u / 52, uc = u - row * 52;
            int gcol = 384 + uc * 8;
            short8v hv;
            if (gcol < NPIX) {
                const float* g = X + (size_t)(row0 + row) * NPIX + gcol;
                f32x4 v0 = *(const f32x4*)(g);
                f32x4 v1 = *(const f32x4*)(g + 4);
                hv = cvt8(v0, v1);
            } else {
                hv = (short8v)(0);
            }
            *(short8v*)(As + row * LSTR + uc * 8) = hv;
        }
    }
    asm volatile("s_waitcnt lgkmcnt(0)" ::: "memory");
    __builtin_amdgcn_s_barrier();              // half-1 visible
    __builtin_amdgcn_sched_barrier(0);

    // ---- kt 12..24 (half-1) ----
    #pragma unroll
    for (int kt = 12; kt < 25; ++kt) {
        if (kt < 24) {
            #pragma unroll
            for (int n = 0; n < 5; ++n)
                bb[(kt + 1) & 1][n] = BP[((w * 5 + n) * 25 + (kt + 1)) * 64 + l];
        }
        const u16* ab = As + lc * LSTR + (kt - 12) * 32 + lk * 8;
        __builtin_amdgcn_s_setprio(1);
        #pragma unroll
        for (int m = 0; m < 4; ++m) {
            short8v a = *(const short8v*)(ab + m * (16 * LSTR));
            #pragma unroll
            for (int n = 0; n < 5; ++n)
                acc[m][n] = __builtin_amdgcn_mfma_f32_16x16x32_bf16(a, bb[kt & 1][n], acc[m][n], 0, 0, 0);
        }
        __builtin_amdgcn_s_setprio(0);
    }
    asm volatile("s_waitcnt lgkmcnt(0)" ::: "memory");
    __builtin_amdgcn_s_barrier();              // all x reads done; As dead
    __builtin_amdgcn_sched_barrier(0);

    // ---- GEMM2 (per-wave strip transpose; r12-verified layout) ----
    u16* strip = As + w * 1536;                // [16][96] bf16 per wave
    {   // zero pad cols 80..95
        uint2 z = make_uint2(0u, 0u);
        *(uint2*)((char*)strip + (l >> 2) * 192 + 160 + (l & 3) * 8) = z;
    }
    float bn[5];
    #pragma unroll
    for (int n = 0; n < 5; ++n) bn[n] = B1[w * 80 + n * 16 + lc];
    const short8v* WP = (const short8v*)W4P2;
    short8v w4f[3];
    #pragma unroll
    for (int kt2 = 0; kt2 < 3; ++kt2)
        w4f[kt2] = WP[(w * 3 + kt2) * 64 + l];

    f32x4 pc[4];
    #pragma unroll
    for (int m = 0; m < 4; ++m) {
        #pragma unroll
        for (int n = 0; n < 5; ++n)
            #pragma unroll
            for (int j = 0; j < 4; ++j)
                strip[(lk * 4 + j) * 96 + n * 16 + lc] = f2bf(fmaxf(acc[m][n][j] + bn[n], 0.0f));
        pc[m] = (f32x4)(0.0f);
        #pragma unroll
        for (int kt2 = 0; kt2 < 3; ++kt2) {
            short8v a2 = *(const short8v*)(strip + lc * 96 + kt2 * 32 + lk * 8);
            pc[m] = __builtin_amdgcn_mfma_f32_16x16x32_bf16(a2, w4f[kt2], pc[m], 0, 0, 0);
        }
    }
    __syncthreads();                           // strips dead; PL overlays As

    float* PLf = (float*)As + w * 640;         // [64][10] f32 per wave
    if (lc < 10) {
        #pragma unroll
        for (int m = 0; m < 4; ++m)
            #pragma unroll
            for (int j = 0; j < 4; ++j)
                PLf[(m * 16 + lk * 4 + j) * 10 + lc] = pc[m][j];
    }
    __syncthreads();

    // ---- combine + bias + log_softmax, one row per thread ----
    if (t < 64) {
        float lg[10];
        #pragma unroll
        for (int o = 0; o < 10; ++o) lg[o] = B4[o];
        #pragma unroll
        for (int w2 = 0; w2 < 10; ++w2) {
            const float* PLw = (const float*)As + w2 * 640;
            #pragma unroll
            for (int o = 0; o < 10; ++o) lg[o] += PLw[t * 10 + o];
        }
        float mx = lg[0];
        #pragma unroll
        for (int o = 1; o < 10; ++o) mx = fmaxf(mx, lg[o]);
        float se = 0.f;
        #pragma unroll
        for (int o = 0; o < 10; ++o) se += expf(lg[o] - mx);
        float lse = logf(se);
        float* op = OUT + (size_t)(row0 + t) * 10;
        #pragma unroll
        for (int o = 0; o < 10; ++o) op[o] = lg[o] - mx - lse;
    }
}

// ---------------------------------------------------------------------------
extern "C" void kernel_launch(void* const* d_in, const int* in_sizes, int n_in,
                              void* d_out, int out_size, void* d_ws, size_t ws_size,
                              hipStream_t stream)
{
    const float* X   = (const float*)d_in[0];
    const float* MRE = (const float*)d_in[1];
    const float* MIM = (const float*)d_in[2];
    const float* W1  = (const float*)d_in[3];
    const float* B1  = (const float*)d_in[4];
    const float* W4  = (const float*)d_in[5];
    const float* B4  = (const float*)d_in[6];
    float* OUT = (float*)d_out;

    float* kre  = (float*)d_ws;                          // 784 f32
    float* flag = kre + 784;                             // 1 f32
    u16*   w1p  = (u16*)((char*)d_ws + 4096);            // 1.28 MB
    u16*   w4p2 = (u16*)((char*)d_ws + 4096 + 1310720);  // 30720 B

    k_kre<<<1, 832, 0, stream>>>(MRE, MIM, kre, flag);
    k_w1pack<<<800, 128, 0, stream>>>(W1, kre, flag, w1p);
    k_w4pack2<<<8, 256, 0, stream>>>(W4, w4p2);
    k_main<<<512, 640, 0, stream>>>(X, w1p, w4p2, B1, B4, OUT);
}